// Round 1
// baseline (568.328 us; speedup 1.0000x reference)
//
#include <hip/hip_runtime.h>
#include <hip/hip_bf16.h>
#include <stdint.h>

typedef __attribute__((ext_vector_type(4))) float f32x4;
typedef __attribute__((ext_vector_type(8))) short short8;

#define B_   64
#define S_   512
#define H_   1024
#define E_   512
#define V_   32000
#define M_   2048            // D*H
#define BS_  32768           // B*S
#define XIN_ 2560            // M_+E_
#define G3_  3072

__device__ __forceinline__ unsigned short f2bf(float f) {
  union { float f; unsigned u; } x; x.f = f;
  unsigned r = x.u + 0x7fffu + ((x.u >> 16) & 1u);
  return (unsigned short)(r >> 16);
}

__device__ __forceinline__ void async16(const void* g, void* l) {
  __builtin_amdgcn_global_load_lds((const __attribute__((address_space(1))) unsigned*)g,
                                   (__attribute__((address_space(3))) unsigned*)l,
                                   16, 0, 0);
}

// ---------------- prep: lin2_w -> bf16, word embedding gather ----------------
__global__ __launch_bounds__(256) void k_prep(const float* __restrict__ lin2w,
                                              unsigned short* __restrict__ bw,
                                              const int* __restrict__ word,
                                              const float* __restrict__ emb,
                                              float* __restrict__ wv) {
  int idx = blockIdx.x * 256 + threadIdx.x;
  const int NC = (H_ * M_) / 4;  // 524288
  if (idx < NC) {
    f32x4 v = *(const f32x4*)(lin2w + (size_t)idx * 4);
    ushort4 o = { f2bf(v.x), f2bf(v.y), f2bf(v.z), f2bf(v.w) };
    *(ushort4*)(bw + (size_t)idx * 4) = o;
  } else {
    int i2 = idx - NC;
    if (i2 < (B_ * E_) / 4) {    // 8192
      int i0 = i2 * 4;
      int b = i0 >> 9;
      int c = i0 & 511;
      f32x4 v = *(const f32x4*)(emb + (size_t)word[b] * E_ + c);
      *(f32x4*)(wv + i0) = v;
    }
  }
}

// ---------------- h_x = hidden @ lin1_w.T + lin1_b + lin2_b ----------------
__global__ __launch_bounds__(256) void k_hx(const float* __restrict__ hidden,
                                            const float* __restrict__ w1,
                                            const float* __restrict__ b1,
                                            const float* __restrict__ b2,
                                            float* __restrict__ hx) {
  int w = threadIdx.x >> 6, l = threadIdx.x & 63;
  int o = blockIdx.x * 4 + w;            // 0..65535
  int b = o >> 10, h = o & 1023;
  const float* hp = hidden + (size_t)b * H_;
  const float* wp = w1 + (size_t)h * H_;
  float s = 0.f;
#pragma unroll
  for (int j = 0; j < 16; ++j) s += hp[l + 64 * j] * wp[l + 64 * j];
#pragma unroll
  for (int off = 32; off; off >>= 1) s += __shfl_down(s, off);
  if (l == 0) hx[o] = s + b1[h] + b2[h];
}

// ---------------- attention GEMM: e_part = sum_h v*tanh(hx + enc@lin2_w.T) ---
// A = enc [32768 x 2048] f32 (reg-staged -> bf16 LDS), B^T = lin2w_bf16 [1024 x 2048]
// tile 128x128, BK=32, 4 waves (2x2), mfma 16x16x32 bf16
__global__ __launch_bounds__(256) void k_attn(const float* __restrict__ enc,
                                              const unsigned short* __restrict__ bw,
                                              const float* __restrict__ hx,
                                              const float* __restrict__ vw,
                                              float* __restrict__ epart) {
  __shared__ unsigned short As[128 * 32];
  __shared__ unsigned short Bs[128 * 32];
  const int bid = blockIdx.x;
  const int bm = bid & 255, bn = bid >> 8;   // same-bm blocks share bid%8 -> same XCD
  const int t = threadIdx.x;
  const int l = t & 63, w = t >> 6;
  const int wr = w >> 1, wc = w & 1;
  const int l15 = l & 15, l4 = l >> 4;

  f32x4 acc[4][4] = {};

  const float* Ag = enc + (size_t)(bm * 128) * M_;
  const unsigned short* Bg = bw + (size_t)(bn * 128) * M_;

  const int ar = t >> 3;           // A stage row (+ j*32)
  const int ac = (t & 7) * 4;      // A stage col
  const int br = t >> 2;           // B stage row (+ i*64)
  const int bc = (t & 3) * 8;      // B stage col

  for (int kt = 0; kt < 64; ++kt) {
    const int k0 = kt * 32;
    // B tile: 8KB via global_load_lds (LDS linear == base + lane*16)
    async16(Bg + (size_t)br * M_ + k0 + bc, (char*)Bs + (size_t)t * 16);
    async16(Bg + (size_t)(br + 64) * M_ + k0 + bc, (char*)Bs + 4096 + (size_t)t * 16);
    // A tile: reg-stage f32 -> bf16
#pragma unroll
    for (int j = 0; j < 4; ++j) {
      f32x4 v = *(const f32x4*)(Ag + (size_t)(ar + j * 32) * M_ + k0 + ac);
      ushort4 o = { f2bf(v.x), f2bf(v.y), f2bf(v.z), f2bf(v.w) };
      *(ushort4*)(As + (ar + j * 32) * 32 + ac) = o;
    }
    __syncthreads();
    short8 af[4], bf[4];
#pragma unroll
    for (int m = 0; m < 4; ++m)
      af[m] = *(const short8*)(As + (wr * 64 + m * 16 + l15) * 32 + l4 * 8);
#pragma unroll
    for (int n = 0; n < 4; ++n)
      bf[n] = *(const short8*)(Bs + (wc * 64 + n * 16 + l15) * 32 + l4 * 8);
#pragma unroll
    for (int m = 0; m < 4; ++m)
#pragma unroll
      for (int n = 0; n < 4; ++n)
        acc[m][n] = __builtin_amdgcn_mfma_f32_16x16x32_bf16(af[m], bf[n], acc[m][n], 0, 0, 0);
    __syncthreads();
  }

  // epilogue: e_part[bn*2+wc][row] = sum over this wave's 64 cols of v*tanh(hx + C)
  const int colbase = bn * 128 + wc * 64;
#pragma unroll
  for (int m = 0; m < 4; ++m) {
#pragma unroll
    for (int j = 0; j < 4; ++j) {
      int rloc = wr * 64 + m * 16 + l4 * 4 + j;
      int rg = bm * 128 + rloc;
      int b = rg >> 9;
      float sum = 0.f;
#pragma unroll
      for (int n = 0; n < 4; ++n) {
        int h = colbase + n * 16 + l15;
        sum += vw[h] * tanhf(hx[b * H_ + h] + acc[m][n][j]);
      }
      sum += __shfl_xor(sum, 1);
      sum += __shfl_xor(sum, 2);
      sum += __shfl_xor(sum, 4);
      sum += __shfl_xor(sum, 8);
      if (l15 == 0) epart[(size_t)(bn * 2 + wc) * BS_ + rg] = sum;
    }
  }
}

// ---------------- softmax over S per batch row (reduces 16 e-partials) ------
__global__ __launch_bounds__(256) void k_softmax(const float* __restrict__ epart,
                                                 float* __restrict__ score) {
  int b = blockIdx.x, t = threadIdx.x;
  float v0 = 0.f, v1 = 0.f;
#pragma unroll
  for (int p = 0; p < 16; ++p) {
    v0 += epart[(size_t)p * BS_ + b * S_ + t];
    v1 += epart[(size_t)p * BS_ + b * S_ + 256 + t];
  }
  int w = t >> 6, l = t & 63;
  float m = fmaxf(v0, v1);
#pragma unroll
  for (int off = 32; off; off >>= 1) m = fmaxf(m, __shfl_xor(m, off));
  __shared__ float sm[4];
  __shared__ float ssum[4];
  if (l == 0) sm[w] = m;
  __syncthreads();
  float M = fmaxf(fmaxf(sm[0], sm[1]), fmaxf(sm[2], sm[3]));
  float p0 = expf(v0 - M), p1 = expf(v1 - M);
  float s = p0 + p1;
#pragma unroll
  for (int off = 32; off; off >>= 1) s += __shfl_xor(s, off);
  if (l == 0) ssum[w] = s;
  __syncthreads();
  float inv = 1.f / (ssum[0] + ssum[1] + ssum[2] + ssum[3]);
  score[b * S_ + t] = p0 * inv;
  score[b * S_ + 256 + t] = p1 * inv;
}

// ---------------- context partials: cpart[sc][b][m] = sum_{s in chunk} score*enc
__global__ __launch_bounds__(256) void k_ctx(const float* __restrict__ enc,
                                             const float* __restrict__ score,
                                             float* __restrict__ cpart) {
  int blk = blockIdx.x;
  int b = blk >> 4, mc = (blk >> 3) & 1, sc = blk & 7;
  int t = threadIdx.x;
  int m = mc * 1024 + t * 4;
  f32x4 acc = {0.f, 0.f, 0.f, 0.f};
  const float* ep = enc + (size_t)b * S_ * M_ + m;
  const float* sp = score + b * S_ + sc * 64;
#pragma unroll 4
  for (int s8 = 0; s8 < 64; ++s8) {
    float sv = sp[s8];
    f32x4 v = *(const f32x4*)(ep + (size_t)(sc * 64 + s8) * M_);
    acc += v * sv;
  }
  *(f32x4*)(cpart + (size_t)sc * (B_ * M_) + b * M_ + m) = acc;
}

__global__ void k_ctxred(const float* __restrict__ cpart, float* __restrict__ ctx) {
  int i0 = (blockIdx.x * 256 + threadIdx.x) * 4;  // 128 blocks -> 131072 elems
  f32x4 a = {0.f, 0.f, 0.f, 0.f};
#pragma unroll
  for (int p = 0; p < 8; ++p) a += *(const f32x4*)(cpart + (size_t)p * (B_ * M_) + i0);
  *(f32x4*)(ctx + i0) = a;
}

// ---------------- GRU input/hidden GEMMs: gi = x@Wih.T+bih, gh = h@Whh.T+bhh -
__global__ __launch_bounds__(256) void k_grugemm(const float* __restrict__ ctx,
                                                 const float* __restrict__ wv,
                                                 const float* __restrict__ hidden,
                                                 const float* __restrict__ Wih,
                                                 const float* __restrict__ bih,
                                                 const float* __restrict__ Whh,
                                                 const float* __restrict__ bhh,
                                                 float* __restrict__ gi,
                                                 float* __restrict__ gh) {
  __shared__ float xs[64][36];
  __shared__ float Ws[16][36];
  const int t = threadIdx.x;
  const bool ghh = blockIdx.x >= 192;
  const int gbase = (ghh ? blockIdx.x - 192 : blockIdx.x) * 16;
  const int K = ghh ? H_ : XIN_;
  const float* Wp = ghh ? Whh : Wih;
  float acc[4] = {0.f, 0.f, 0.f, 0.f};
  const int g = t & 15, bb = t >> 4;
  const int srow = t >> 2, sc0 = (t & 3) * 8;
  const int wrow = t >> 3, wc0 = (t & 7) * 4;
  for (int kc = 0; kc < K; kc += 32) {
    f32x4 xa, xb;
    if (ghh) {
      xa = *(const f32x4*)(hidden + (size_t)srow * H_ + kc + sc0);
      xb = *(const f32x4*)(hidden + (size_t)srow * H_ + kc + sc0 + 4);
    } else if (kc + sc0 < M_) {
      xa = *(const f32x4*)(ctx + (size_t)srow * M_ + kc + sc0);
      xb = *(const f32x4*)(ctx + (size_t)srow * M_ + kc + sc0 + 4);
    } else {
      xa = *(const f32x4*)(wv + (size_t)srow * E_ + kc + sc0 - M_);
      xb = *(const f32x4*)(wv + (size_t)srow * E_ + kc + sc0 - M_ + 4);
    }
    *(f32x4*)&xs[srow][sc0] = xa;
    *(f32x4*)&xs[srow][sc0 + 4] = xb;
    if (t < 128) {
      f32x4 w4 = *(const f32x4*)(Wp + (size_t)(gbase + wrow) * K + kc + wc0);
      *(f32x4*)&Ws[wrow][wc0] = w4;
    }
    __syncthreads();
#pragma unroll
    for (int kk = 0; kk < 32; ++kk) {
      float wgt = Ws[g][kk];
#pragma unroll
      for (int i = 0; i < 4; ++i) acc[i] += xs[bb * 4 + i][kk] * wgt;
    }
    __syncthreads();
  }
  float* dst = ghh ? gh : gi;
  const float* bias = ghh ? bhh : bih;
#pragma unroll
  for (int i = 0; i < 4; ++i)
    dst[(size_t)(bb * 4 + i) * G3_ + gbase + g] = acc[i] + bias[gbase + g];
}

// ---------------- GRU gates -> new_hidden ----------------
__global__ void k_gate(const float* __restrict__ gi, const float* __restrict__ gh,
                       const float* __restrict__ hidden, float* __restrict__ newh) {
  int o = blockIdx.x * 256 + threadIdx.x;  // 65536
  int b = o >> 10, h = o & 1023;
  const float* gib = gi + (size_t)b * G3_;
  const float* ghb = gh + (size_t)b * G3_;
  float r = 1.f / (1.f + expf(-(gib[h] + ghb[h])));
  float z = 1.f / (1.f + expf(-(gib[1024 + h] + ghb[1024 + h])));
  float n = tanhf(gib[2048 + h] + r * ghb[2048 + h]);
  newh[o] = (1.f - z) * n + z * hidden[o];
}

// ---------------- output projection: pred = newh @ out_w.T + out_b ----------
__global__ __launch_bounds__(256) void k_outproj(const float* __restrict__ newh,
                                                 const float* __restrict__ ow,
                                                 const float* __restrict__ ob,
                                                 float* __restrict__ pred) {
  __shared__ float hs[64][36];
  __shared__ float Ws[64][36];
  const int t = threadIdx.x;
  const int vbase = blockIdx.x * 64;
  const int vb = t & 15, bb = t >> 4;
  const int srow = t >> 2, sc0 = (t & 3) * 8;
  float acc[4][4] = {};
  for (int kc = 0; kc < H_; kc += 32) {
    *(f32x4*)&hs[srow][sc0]     = *(const f32x4*)(newh + (size_t)srow * H_ + kc + sc0);
    *(f32x4*)&hs[srow][sc0 + 4] = *(const f32x4*)(newh + (size_t)srow * H_ + kc + sc0 + 4);
    *(f32x4*)&Ws[srow][sc0]     = *(const f32x4*)(ow + (size_t)(vbase + srow) * H_ + kc + sc0);
    *(f32x4*)&Ws[srow][sc0 + 4] = *(const f32x4*)(ow + (size_t)(vbase + srow) * H_ + kc + sc0 + 4);
    __syncthreads();
#pragma unroll
    for (int kk = 0; kk < 32; ++kk) {
      float a[4], w4[4];
#pragma unroll
      for (int i = 0; i < 4; ++i) a[i] = hs[bb * 4 + i][kk];
#pragma unroll
      for (int j = 0; j < 4; ++j) w4[j] = Ws[vb + 16 * j][kk];
#pragma unroll
      for (int i = 0; i < 4; ++i)
#pragma unroll
        for (int j = 0; j < 4; ++j) acc[i][j] += a[i] * w4[j];
    }
    __syncthreads();
  }
#pragma unroll
  for (int i = 0; i < 4; ++i)
#pragma unroll
    for (int j = 0; j < 4; ++j)
      pred[(size_t)(bb * 4 + i) * V_ + vbase + vb + 16 * j] = acc[i][j] + ob[vbase + vb + 16 * j];
}

extern "C" void kernel_launch(void* const* d_in, const int* in_sizes, int n_in,
                              void* d_out, int out_size, void* d_ws, size_t ws_size,
                              hipStream_t stream) {
  const int*   word   = (const int*)d_in[0];
  const float* hidden = (const float*)d_in[1];
  const float* enc    = (const float*)d_in[2];
  // d_in[3] output_distribution: unused by reference
  // d_in[4] encoder_attention:   unused by reference
  const float* emb    = (const float*)d_in[5];
  const float* lin1w  = (const float*)d_in[6];
  const float* lin1b  = (const float*)d_in[7];
  const float* lin2w  = (const float*)d_in[8];
  const float* lin2b  = (const float*)d_in[9];
  const float* vw     = (const float*)d_in[10];
  // d_in[11] v_b: softmax is shift-invariant -> dropped
  const float* Wih    = (const float*)d_in[12];
  const float* bih    = (const float*)d_in[13];
  const float* Whh    = (const float*)d_in[14];
  const float* bhh    = (const float*)d_in[15];
  const float* ow     = (const float*)d_in[16];
  const float* ob     = (const float*)d_in[17];

  float* out   = (float*)d_out;
  float* pred  = out;                   // [64][32000]
  float* newh  = out + 2048000;         // [64][1024]
  float* score = out + 2113536;         // [64][512]

  char* ws = (char*)d_ws;
  unsigned short* bw = (unsigned short*)ws;         // lin2_w bf16: 4,194,304 B
  float* hx    = (float*)(ws + 4194304);            // 262,144 B
  float* wvbuf = (float*)(ws + 4456448);            // 131,072 B
  float* epart = (float*)(ws + 4587520);            // 16*32768*4 = 2,097,152 B
  float* cpart = (float*)(ws + 6684672);            // 8*131072*4 = 4,194,304 B
  float* ctx   = (float*)(ws + 10878976);           // 524,288 B
  float* gi    = (float*)(ws + 11403264);           // 786,432 B
  float* gh    = (float*)(ws + 12189696);           // 786,432 B (end ~12.98 MB)

  k_prep<<<2080, 256, 0, stream>>>(lin2w, bw, word, emb, wvbuf);
  k_hx<<<16384, 256, 0, stream>>>(hidden, lin1w, lin1b, lin2b, hx);
  k_attn<<<2048, 256, 0, stream>>>(enc, bw, hx, vw, epart);
  k_softmax<<<64, 256, 0, stream>>>(epart, score);
  k_ctx<<<1024, 256, 0, stream>>>(enc, score, cpart);
  k_ctxred<<<128, 256, 0, stream>>>(cpart, ctx);
  k_grugemm<<<384, 256, 0, stream>>>(ctx, wvbuf, hidden, Wih, bih, Whh, bhh, gi, gh);
  k_gate<<<256, 256, 0, stream>>>(gi, gh, hidden, newh);
  k_outproj<<<500, 256, 0, stream>>>(newh, ow, ob, pred);
}